// Round 1
// baseline (740.528 us; speedup 1.0000x reference)
//
#include <hip/hip_runtime.h>
#include <hip/hip_bf16.h>

#define N_NODES   100000
#define N_EDGES   1600000
#define CH        128
#define N_GRAPHS  512
#define N_CLASSES 64
#define BN_EPS    1e-5f
#define N_PAD     100128   /* N_NODES rounded up past 128-row gemm tile */

typedef unsigned int uint;
typedef unsigned short ushort_t;

typedef short bf16x8 __attribute__((ext_vector_type(8)));
typedef float f32x4  __attribute__((ext_vector_type(4)));

__device__ __forceinline__ ushort_t f2bf(float f) {
    uint u = __float_as_uint(f);
    uint r = (u + 0x7fffu + ((u >> 16) & 1u)) >> 16;   // round-to-nearest-even
    return (ushort_t)r;
}
__device__ __forceinline__ float bf2f(ushort_t u) {
    return __uint_as_float(((uint)u) << 16);
}
__device__ __forceinline__ float bf2f_lo(uint u) {      // low bf16 of a dword
    return __uint_as_float(u << 16);
}
__device__ __forceinline__ float bf2f_hi(uint u) {      // high bf16 of a dword
    return __uint_as_float(u & 0xffff0000u);
}

// ---------------- degree count + per-edge rank ----------------
__global__ __launch_bounds__(256) void k_deg(const int* __restrict__ dst,
                                             int* __restrict__ cnt,
                                             int* __restrict__ rank) {
    int e = blockIdx.x * 256 + threadIdx.x;
    if (e < N_EDGES) rank[e] = atomicAdd(&cnt[dst[e]], 1);
}

// ---------------- exclusive scan (3-kernel, 100K elems) ----------------
__global__ __launch_bounds__(512) void k_scan1(const int* __restrict__ cnt,
                                               int* __restrict__ lofs,
                                               int* __restrict__ bsum) {
    __shared__ int sd[512];
    int t = threadIdx.x;
    int i = blockIdx.x * 512 + t;
    int v = (i < N_NODES) ? cnt[i] : 0;
    sd[t] = v;
    __syncthreads();
    for (int o = 1; o < 512; o <<= 1) {
        int x = (t >= o) ? sd[t - o] : 0;
        __syncthreads();
        sd[t] += x;
        __syncthreads();
    }
    if (i < N_NODES) lofs[i] = sd[t] - v;     // exclusive
    if (t == 511) bsum[blockIdx.x] = sd[511];
}

// parallel LDS scan of block sums (196 <= 256)
__global__ __launch_bounds__(256) void k_scan2(int* __restrict__ bsum, int nblocks) {
    __shared__ int sd[256];
    int t = threadIdx.x;
    int v = (t < nblocks) ? bsum[t] : 0;
    sd[t] = v;
    __syncthreads();
    for (int o = 1; o < 256; o <<= 1) {
        int x = (t >= o) ? sd[t - o] : 0;
        __syncthreads();
        sd[t] += x;
        __syncthreads();
    }
    if (t < nblocks) bsum[t] = sd[t] - v;     // exclusive
}

// final offsets + dinv (fused)
__global__ __launch_bounds__(256) void k_scan3(const int* __restrict__ lofs,
                                               const int* __restrict__ bsum,
                                               const int* __restrict__ cnt,
                                               int* __restrict__ offs,
                                               float* __restrict__ dinv) {
    int i = blockIdx.x * 256 + threadIdx.x;
    if (i < N_NODES) {
        offs[i] = lofs[i] + bsum[i >> 9];
        dinv[i] = rsqrtf((float)cnt[i] + 1.0f);
    }
    if (i == 0) offs[N_NODES] = N_EDGES;
}

// ---------------- CSR fill (no atomics: rank precomputed) ----------------
__global__ __launch_bounds__(256) void k_fill(const int* __restrict__ src,
                                              const int* __restrict__ dst,
                                              const int* __restrict__ offs,
                                              const int* __restrict__ rank,
                                              int* __restrict__ csr_src) {
    int e = blockIdx.x * 256 + threadIdx.x;
    if (e >= N_EDGES) return;
    int pos = offs[dst[e]] + rank[e];
    csr_src[pos] = src[e];
}

// ---------------- fused weight transpose + x cast ----------------
// blocks [0,192): Wt[l][n*128+k] = bf16(W_l[k*128+n]);  blocks [192,...): x -> bf16
#define PREP_BLOCKS 192
__global__ __launch_bounds__(256) void k_precast(const float* __restrict__ W1,
                                                 const float* __restrict__ W2,
                                                 const float* __restrict__ W3,
                                                 ushort_t* __restrict__ Wt,
                                                 const float* __restrict__ x,
                                                 ushort_t* __restrict__ XB) {
    if (blockIdx.x < PREP_BLOCKS) {
        int tid = blockIdx.x * 256 + threadIdx.x;      // < 3*16384
        int l = tid >> 14;
        int e = tid & 16383;
        int n = e >> 7;
        int k = e & 127;
        const float* W = (l == 0) ? W1 : (l == 1) ? W2 : W3;
        Wt[l * 16384 + n * 128 + k] = f2bf(W[k * 128 + n]);
    } else {
        int tid = (blockIdx.x - PREP_BLOCKS) * 256 + threadIdx.x;
        if (tid >= N_NODES * 32) return;
        int i = tid >> 5;
        int c = (tid & 31) * 4;
        float4 v = *(const float4*)&x[(size_t)i * 128 + c];
        ushort4 o;
        o.x = f2bf(v.x); o.y = f2bf(v.y); o.z = f2bf(v.z); o.w = f2bf(v.w);
        *(ushort4*)&XB[(size_t)i * 128 + c] = o;
    }
}

// ---------------- MFMA GEMM: Hs(bf16) = dinv * (XB(bf16) @ W) ----------------
// Each wave owns 32 rows x 128 cols: A rows are read ONCE per block (was 2x),
// B (32KB Wt) is re-read from L2 which is free.
__global__ __launch_bounds__(256) void k_gemm(const ushort_t* __restrict__ XB,
                                              const ushort_t* __restrict__ Wt,
                                              const float* __restrict__ dinv,
                                              ushort_t* __restrict__ H) {
    const int t = threadIdx.x;
    const int wave = t >> 6;
    const int lane = t & 63;
    const int q = lane >> 4;       // quad 0..3
    const int r = lane & 15;
    const int row0 = blockIdx.x * 128 + wave * 32;

    f32x4 acc[2][8];
#pragma unroll
    for (int i = 0; i < 2; ++i)
#pragma unroll
        for (int j = 0; j < 8; ++j)
            acc[i][j] = (f32x4){0.f, 0.f, 0.f, 0.f};

#pragma unroll
    for (int ks = 0; ks < 4; ++ks) {
        const int k0 = ks * 32 + q * 8;
        bf16x8 a[2], b[8];
#pragma unroll
        for (int i = 0; i < 2; ++i)
            a[i] = *(const bf16x8*)(XB + (size_t)(row0 + i * 16 + r) * 128 + k0);
#pragma unroll
        for (int j = 0; j < 8; ++j)
            b[j] = *(const bf16x8*)(Wt + (size_t)(j * 16 + r) * 128 + k0);
#pragma unroll
        for (int i = 0; i < 2; ++i)
#pragma unroll
            for (int j = 0; j < 8; ++j)
                acc[i][j] = __builtin_amdgcn_mfma_f32_16x16x32_bf16(a[i], b[j], acc[i][j], 0, 0, 0);
    }

#pragma unroll
    for (int i = 0; i < 2; ++i) {
#pragma unroll
        for (int rg = 0; rg < 4; ++rg) {
            int rr = row0 + i * 16 + q * 4 + rg;
            if (rr < N_NODES) {
                float dv = dinv[rr];
#pragma unroll
                for (int j = 0; j < 8; ++j)
                    H[(size_t)rr * 128 + j * 16 + r] = f2bf(acc[i][j][rg] * dv);
            }
        }
    }
}

// ---------------- gather-aggregate v3: one wave per dst node, 4 edges per pass ----------------
// 16 lanes per edge, uint4 (16B) loads: half the vmem instructions per byte vs v2.
// AGG (bf16) = dinv[i]*(sum_nbr Hs + Hs[i]) + b
__global__ __launch_bounds__(256) void k_gather(const int* __restrict__ csr_src,
                                                const int* __restrict__ offs,
                                                const float* __restrict__ dinv,
                                                const ushort_t* __restrict__ H,
                                                const float* __restrict__ b,
                                                ushort_t* __restrict__ AGG) {
    int node = blockIdx.x * 4 + (threadIdx.x >> 6);
    if (node >= N_NODES) return;
    int lane = threadIdx.x & 63;
    int g = lane >> 4;             // edge slot within the quad (0..3)
    int cl = lane & 15;
    int c = cl * 8;                // 8 channels per lane

    float a0 = 0.f, a1 = 0.f, a2 = 0.f, a3 = 0.f;
    float a4 = 0.f, a5 = 0.f, a6 = 0.f, a7 = 0.f;

#define ACC8(hv)  do { \
        a0 += bf2f_lo((hv).x); a1 += bf2f_hi((hv).x); \
        a2 += bf2f_lo((hv).y); a3 += bf2f_hi((hv).y); \
        a4 += bf2f_lo((hv).z); a5 += bf2f_hi((hv).z); \
        a6 += bf2f_lo((hv).w); a7 += bf2f_hi((hv).w); } while (0)

    if (g == 0) {                  // self term (dinv-scaled H row)
        uint4 hv = *(const uint4*)(H + (size_t)node * 128 + c);
        ACC8(hv);
    }

    int p = offs[node];
    int end = offs[node + 1];

    for (; p + 16 <= end; p += 16) {          // 16 edges: 4 quad-loads in flight
        int s0 = csr_src[p      + g], s1 = csr_src[p +  4 + g];
        int s2 = csr_src[p +  8 + g], s3 = csr_src[p + 12 + g];
        uint4 h0 = *(const uint4*)(H + (size_t)s0 * 128 + c);
        uint4 h1 = *(const uint4*)(H + (size_t)s1 * 128 + c);
        uint4 h2 = *(const uint4*)(H + (size_t)s2 * 128 + c);
        uint4 h3 = *(const uint4*)(H + (size_t)s3 * 128 + c);
        ACC8(h0); ACC8(h1); ACC8(h2); ACC8(h3);
    }
    for (; p + 4 <= end; p += 4) {            // 4 edges: 1 quad-load
        int s0 = csr_src[p + g];
        uint4 h0 = *(const uint4*)(H + (size_t)s0 * 128 + c);
        ACC8(h0);
    }
    if (p < end) {                            // tail: 1-3 edges, predicated
        int idx = p + g;
        bool ok = idx < end;
        int s0 = csr_src[ok ? idx : p];
        uint4 h0 = *(const uint4*)(H + (size_t)s0 * 128 + c);
        if (ok) ACC8(h0);
    }
#undef ACC8

    // combine the 4 edge groups: xor 16 then xor 32
    a0 += __shfl_xor(a0, 16); a1 += __shfl_xor(a1, 16);
    a2 += __shfl_xor(a2, 16); a3 += __shfl_xor(a3, 16);
    a4 += __shfl_xor(a4, 16); a5 += __shfl_xor(a5, 16);
    a6 += __shfl_xor(a6, 16); a7 += __shfl_xor(a7, 16);
    a0 += __shfl_xor(a0, 32); a1 += __shfl_xor(a1, 32);
    a2 += __shfl_xor(a2, 32); a3 += __shfl_xor(a3, 32);
    a4 += __shfl_xor(a4, 32); a5 += __shfl_xor(a5, 32);
    a6 += __shfl_xor(a6, 32); a7 += __shfl_xor(a7, 32);

    if (g == 0) {
        float dv = dinv[node];
        float4 bv0 = *(const float4*)&b[c];
        float4 bv1 = *(const float4*)&b[c + 4];
        a0 = a0 * dv + bv0.x; a1 = a1 * dv + bv0.y;
        a2 = a2 * dv + bv0.z; a3 = a3 * dv + bv0.w;
        a4 = a4 * dv + bv1.x; a5 = a5 * dv + bv1.y;
        a6 = a6 * dv + bv1.z; a7 = a7 * dv + bv1.w;
        uint4 o;
        o.x = (uint)f2bf(a0) | ((uint)f2bf(a1) << 16);
        o.y = (uint)f2bf(a2) | ((uint)f2bf(a3) << 16);
        o.z = (uint)f2bf(a4) | ((uint)f2bf(a5) << 16);
        o.w = (uint)f2bf(a6) | ((uint)f2bf(a7) << 16);
        *(uint4*)(AGG + (size_t)node * 128 + c) = o;
    }
}

// ---------------- BN stats: per-channel sum / sumsq (bf16 in) ----------------
__global__ __launch_bounds__(128) void k_bn_stats(const ushort_t* __restrict__ AGG,
                                                  float* __restrict__ stats) {
    int c = threadIdx.x;
    float s = 0.f, q = 0.f;
    for (int i = blockIdx.x; i < N_NODES; i += gridDim.x) {
        float v = bf2f(AGG[(size_t)i * 128 + c]);
        s += v;
        q += v * v;
    }
    atomicAdd(&stats[c], s);
    atomicAdd(&stats[128 + c], q);
}

// ---------------- BN apply (finalize fused) + ReLU (+ bf16 residual), bf16 out ----------------
__global__ __launch_bounds__(256) void k_bn_apply(const ushort_t* __restrict__ AGG,
                                                  const float* __restrict__ stats,
                                                  const float* __restrict__ gamma,
                                                  const float* __restrict__ beta,
                                                  const ushort_t* __restrict__ RES,  // may be null
                                                  ushort_t* __restrict__ OUT) {
    int tid = blockIdx.x * 256 + threadIdx.x;
    if (tid >= N_NODES * 32) return;
    int i = tid >> 5;
    int c = (tid & 31) * 4;

    const float invN = 1.0f / (float)N_NODES;
    float4 sm = *(const float4*)&stats[c];
    float4 sq = *(const float4*)&stats[128 + c];
    float4 gm = *(const float4*)&gamma[c];
    float4 bt = *(const float4*)&beta[c];
    float mu0 = sm.x * invN, mu1 = sm.y * invN, mu2 = sm.z * invN, mu3 = sm.w * invN;
    float sc0 = gm.x * rsqrtf(sq.x * invN - mu0 * mu0 + BN_EPS);
    float sc1 = gm.y * rsqrtf(sq.y * invN - mu1 * mu1 + BN_EPS);
    float sc2 = gm.z * rsqrtf(sq.z * invN - mu2 * mu2 + BN_EPS);
    float sc3 = gm.w * rsqrtf(sq.w * invN - mu3 * mu3 + BN_EPS);
    float sh0 = bt.x - mu0 * sc0, sh1 = bt.y - mu1 * sc1;
    float sh2 = bt.z - mu2 * sc2, sh3 = bt.w - mu3 * sc3;

    uint2 av = *(const uint2*)&AGG[(size_t)i * 128 + c];
    float y0 = bf2f((ushort_t)(av.x & 0xffff)) * sc0 + sh0;
    float y1 = bf2f((ushort_t)(av.x >> 16))    * sc1 + sh1;
    float y2 = bf2f((ushort_t)(av.y & 0xffff)) * sc2 + sh2;
    float y3 = bf2f((ushort_t)(av.y >> 16))    * sc3 + sh3;
    if (RES) {
        ushort4 rv = *(const ushort4*)&RES[(size_t)i * 128 + c];
        y0 += bf2f(rv.x); y1 += bf2f(rv.y); y2 += bf2f(rv.z); y3 += bf2f(rv.w);
    }
    ushort4 o;
    o.x = f2bf(fmaxf(y0, 0.f)); o.y = f2bf(fmaxf(y1, 0.f));
    o.z = f2bf(fmaxf(y2, 0.f)); o.w = f2bf(fmaxf(y3, 0.f));
    *(ushort4*)&OUT[(size_t)i * 128 + c] = o;
}

// ---------------- pooling: segmented reduction over sorted batch (bf16 in) ----------------
#define POOL_CHUNK 100
__global__ __launch_bounds__(128) void k_pool(const ushort_t* __restrict__ X,
                                              const int* __restrict__ batch,
                                              float* __restrict__ psum,
                                              uint* __restrict__ pmax,
                                              float* __restrict__ pcnt) {
    int t = threadIdx.x;                        // channel
    int i0 = blockIdx.x * POOL_CHUNK;
    int i1 = min(i0 + POOL_CHUNK, N_NODES);
    if (i0 >= i1) return;

    int cur = batch[i0];
    float s = 0.f, m = 0.f, cntf = 0.f;
    for (int i = i0; i < i1; ++i) {
        int b = batch[i];
        float v = bf2f(X[(size_t)i * 128 + t]);
        if (b != cur) {
            atomicAdd(&psum[cur * 128 + t], s);
            atomicMax(&pmax[cur * 128 + t], __float_as_uint(m));
            if (t == 0) atomicAdd(&pcnt[cur], cntf);
            s = 0.f; m = 0.f; cntf = 0.f;
            cur = b;
        }
        s += v;
        m = fmaxf(m, v);
        cntf += 1.f;
    }
    atomicAdd(&psum[cur * 128 + t], s);
    atomicMax(&pmax[cur * 128 + t], __float_as_uint(m));
    if (t == 0) atomicAdd(&pcnt[cur], cntf);
}

// ---------------- head ----------------
__global__ __launch_bounds__(64) void k_head(const float* __restrict__ psum,
                                             const uint* __restrict__ pmax,
                                             const float* __restrict__ pcnt,
                                             const float* __restrict__ Wh,
                                             const float* __restrict__ bh,
                                             float* __restrict__ out) {
    int g = blockIdx.x;
    int o = threadIdx.x;
    float cnt = pcnt[g];
    float inv = 1.0f / fmaxf(cnt, 1.0f);
    float acc = bh[o];
    for (int c = 0; c < 128; ++c) {
        float s = psum[g * 128 + c];
        float m = __uint_as_float(pmax[g * 128 + c]);
        acc += (s * inv) * Wh[c * 64 + o];
        acc += s * Wh[(128 + c) * 64 + o];
        acc += m * Wh[(256 + c) * 64 + o];
    }
    out[g * 64 + o] = acc;
}

// ---------------- host orchestration ----------------
extern "C" void kernel_launch(void* const* d_in, const int* in_sizes, int n_in,
                              void* d_out, int out_size, void* d_ws, size_t ws_size,
                              hipStream_t stream) {
    const float* x     = (const float*)d_in[0];
    const int*   ei    = (const int*)d_in[1];
    const int*   batch = (const int*)d_in[2];
    const float* W1 = (const float*)d_in[3];
    const float* b1 = (const float*)d_in[4];
    const float* g1 = (const float*)d_in[5];
    const float* be1= (const float*)d_in[6];
    const float* W2 = (const float*)d_in[7];
    const float* b2 = (const float*)d_in[8];
    const float* g2 = (const float*)d_in[9];
    const float* be2= (const float*)d_in[10];
    const float* W3 = (const float*)d_in[11];
    const float* b3 = (const float*)d_in[12];
    const float* g3 = (const float*)d_in[13];
    const float* be3= (const float*)d_in[14];
    const float* Wh = (const float*)d_in[15];
    const float* bh = (const float*)d_in[16];

    const int* src = ei;
    const int* dst = ei + N_EDGES;

    char* ws = (char*)d_ws;
    size_t off = 0;

    // ---- zero-initialized contiguous region (single memset) ----
    char* zero_base = ws;
    int*   cnt     = (int*)(ws + off);      off += 400384;                       // N_NODES*4 padded
    float* stats   = (float*)(ws + off);    off += 3 * 512 * 4;                  // 3 layers x 512 floats
    float* psum    = (float*)(ws + off);    off += (size_t)N_GRAPHS * CH * 4;
    uint*  pmax    = (uint*)(ws + off);     off += (size_t)N_GRAPHS * CH * 4;
    float* pcnt    = (float*)(ws + off);    off += 4096;
    size_t zero_bytes = off;

    // ---- uninitialized scratch ----
    float* dinv    = (float*)(ws + off);    off += 512 * 1024;
    ushort_t* XBA  = (ushort_t*)(ws + off); off += (size_t)N_PAD * CH * 2;
    ushort_t* XBB  = (ushort_t*)(ws + off); off += (size_t)N_PAD * CH * 2;
    ushort_t* H    = (ushort_t*)(ws + off); off += (size_t)N_PAD * CH * 2;
    ushort_t* AGG  = (ushort_t*)(ws + off); off += (size_t)N_NODES * CH * 2;
    ushort_t* Wt   = (ushort_t*)(ws + off); off += 3 * 16384 * 2;
    int*   lofs    = (int*)(ws + off);      off += 512 * 1024;
    int*   offs    = (int*)(ws + off);      off += 512 * 1024;      // N+1 ints
    int*   bsum    = (int*)(ws + off);      off += 4096;
    int*   rank    = (int*)(ws + off);      off += (size_t)N_EDGES * 4;
    int*   csr_src = (int*)(ws + off);      off += (size_t)N_EDGES * 4;

    const int SCAN_BLOCKS = (N_NODES + 511) / 512;   // 196

    hipMemsetAsync(zero_base, 0, zero_bytes, stream);

    // fused weight transpose + x cast
    const int cast_blocks = (N_NODES * 32 + 255) / 256;
    k_precast<<<PREP_BLOCKS + cast_blocks, 256, 0, stream>>>(W1, W2, W3, Wt, x, XBA);

    // degree(+rank) / scan(+dinv) / CSR fill
    k_deg<<<(N_EDGES + 255) / 256, 256, 0, stream>>>(dst, cnt, rank);
    k_scan1<<<SCAN_BLOCKS, 512, 0, stream>>>(cnt, lofs, bsum);
    k_scan2<<<1, 256, 0, stream>>>(bsum, SCAN_BLOCKS);
    k_scan3<<<(N_NODES + 255) / 256, 256, 0, stream>>>(lofs, bsum, cnt, offs, dinv);
    k_fill<<<(N_EDGES + 255) / 256, 256, 0, stream>>>(src, dst, offs, rank, csr_src);

    const int gemm_grid   = (N_NODES + 127) / 128;   // 782
    const int gather_grid = (N_NODES + 3) / 4;
    const int apply_grid  = (N_NODES * 32 + 255) / 256;
    const int pool_grid   = (N_NODES + POOL_CHUNK - 1) / POOL_CHUNK;

    struct Layer { const ushort_t* in; ushort_t* out; const ushort_t* Wt; const float* b;
                   const float* gm; const float* bt; const ushort_t* res; };
    Layer layers[3] = {
        { XBA, XBB, Wt,             b1, g1, be1, nullptr },
        { XBB, XBA, Wt + 16384,     b2, g2, be2, XBB     },
        { XBA, XBB, Wt + 2 * 16384, b3, g3, be3, XBA     },
    };

    for (int l = 0; l < 3; ++l) {
        const Layer& L = layers[l];
        float* st = stats + l * 512;
        k_gemm<<<gemm_grid, 256, 0, stream>>>(L.in, L.Wt, dinv, H);
        k_gather<<<gather_grid, 256, 0, stream>>>(csr_src, offs, dinv, H, L.b, AGG);
        k_bn_stats<<<1024, 128, 0, stream>>>(AGG, st);
        k_bn_apply<<<apply_grid, 256, 0, stream>>>(AGG, st, L.gm, L.bt, L.res, L.out);
    }

    // pooling (layer-3 output is in XBB)
    k_pool<<<pool_grid, 128, 0, stream>>>(XBB, batch, psum, pmax, pcnt);
    k_head<<<N_GRAPHS, 64, 0, stream>>>(psum, pmax, pcnt, Wh, bh, (float*)d_out);
}

// Round 2
// 726.146 us; speedup vs baseline: 1.0198x; 1.0198x over previous
//
#include <hip/hip_runtime.h>
#include <hip/hip_bf16.h>

#define N_NODES   100000
#define N_EDGES   1600000
#define CH        128
#define N_GRAPHS  512
#define N_CLASSES 64
#define BN_EPS    1e-5f
#define N_PAD     100128   /* N_NODES rounded up past 128-row gemm tile */
#define CNT_STRIDE 16      /* one 64B cache line per degree counter (atomic spread) */

typedef unsigned int uint;
typedef unsigned short ushort_t;

typedef short bf16x8 __attribute__((ext_vector_type(8)));
typedef float f32x4  __attribute__((ext_vector_type(4)));

__device__ __forceinline__ ushort_t f2bf(float f) {
    uint u = __float_as_uint(f);
    uint r = (u + 0x7fffu + ((u >> 16) & 1u)) >> 16;   // round-to-nearest-even
    return (ushort_t)r;
}
__device__ __forceinline__ float bf2f(ushort_t u) {
    return __uint_as_float(((uint)u) << 16);
}
__device__ __forceinline__ float bf2f_lo(uint u) {      // low bf16 of a dword
    return __uint_as_float(u << 16);
}
__device__ __forceinline__ float bf2f_hi(uint u) {      // high bf16 of a dword
    return __uint_as_float(u & 0xffff0000u);
}

// ---------------- degree count + per-edge rank ----------------
// cnt is padded: one counter per 64B line, so same-line atomic serialization is
// only same-node (deg ~16) instead of 16 nodes x 16 (256) per line.
__global__ __launch_bounds__(256) void k_deg(const int* __restrict__ dst,
                                             int* __restrict__ cnt,
                                             int* __restrict__ rank) {
    int e = blockIdx.x * 256 + threadIdx.x;
    if (e < N_EDGES) rank[e] = atomicAdd(&cnt[dst[e] * CNT_STRIDE], 1);
}

// ---------------- exclusive scan (3-kernel, 100K elems) ----------------
__global__ __launch_bounds__(512) void k_scan1(const int* __restrict__ cnt,
                                               int* __restrict__ lofs,
                                               int* __restrict__ bsum) {
    __shared__ int sd[512];
    int t = threadIdx.x;
    int i = blockIdx.x * 512 + t;
    int v = (i < N_NODES) ? cnt[i * CNT_STRIDE] : 0;
    sd[t] = v;
    __syncthreads();
    for (int o = 1; o < 512; o <<= 1) {
        int x = (t >= o) ? sd[t - o] : 0;
        __syncthreads();
        sd[t] += x;
        __syncthreads();
    }
    if (i < N_NODES) lofs[i] = sd[t] - v;     // exclusive
    if (t == 511) bsum[blockIdx.x] = sd[511];
}

// parallel LDS scan of block sums (196 <= 256)
__global__ __launch_bounds__(256) void k_scan2(int* __restrict__ bsum, int nblocks) {
    __shared__ int sd[256];
    int t = threadIdx.x;
    int v = (t < nblocks) ? bsum[t] : 0;
    sd[t] = v;
    __syncthreads();
    for (int o = 1; o < 256; o <<= 1) {
        int x = (t >= o) ? sd[t - o] : 0;
        __syncthreads();
        sd[t] += x;
        __syncthreads();
    }
    if (t < nblocks) bsum[t] = sd[t] - v;     // exclusive
}

// final offsets + dinv (fused)
__global__ __launch_bounds__(256) void k_scan3(const int* __restrict__ lofs,
                                               const int* __restrict__ bsum,
                                               const int* __restrict__ cnt,
                                               int* __restrict__ offs,
                                               float* __restrict__ dinv) {
    int i = blockIdx.x * 256 + threadIdx.x;
    if (i < N_NODES) {
        offs[i] = lofs[i] + bsum[i >> 9];
        dinv[i] = rsqrtf((float)cnt[i * CNT_STRIDE] + 1.0f);
    }
    if (i == 0) offs[N_NODES] = N_EDGES;
}

// ---------------- CSR fill (no atomics: rank precomputed) ----------------
__global__ __launch_bounds__(256) void k_fill(const int* __restrict__ src,
                                              const int* __restrict__ dst,
                                              const int* __restrict__ offs,
                                              const int* __restrict__ rank,
                                              int* __restrict__ csr_src) {
    int e = blockIdx.x * 256 + threadIdx.x;
    if (e >= N_EDGES) return;
    int pos = offs[dst[e]] + rank[e];
    csr_src[pos] = src[e];
}

// ---------------- weight transpose + bf16 cast (x cast now fused into gemm L1) ----
// Wt[l][n*128+k] = bf16(W_l[k*128+n])
#define PREP_BLOCKS 192
__global__ __launch_bounds__(256) void k_precast(const float* __restrict__ W1,
                                                 const float* __restrict__ W2,
                                                 const float* __restrict__ W3,
                                                 ushort_t* __restrict__ Wt) {
    int tid = blockIdx.x * 256 + threadIdx.x;      // < 3*16384
    int l = tid >> 14;
    int e = tid & 16383;
    int n = e >> 7;
    int k = e & 127;
    const float* W = (l == 0) ? W1 : (l == 1) ? W2 : W3;
    Wt[l * 16384 + n * 128 + k] = f2bf(W[k * 128 + n]);
}

// ---------------- MFMA GEMM: Hs(bf16) = dinv * (A @ W) ----------------
// Each wave owns 32 rows x 128 cols; A rows read once per block.
// F32A: A is the raw f32 input x, converted in-register via the same f2bf
// (bit-identical to the old pre-cast path; saves the 77MB precast pass).
template<bool F32A>
__global__ __launch_bounds__(256) void k_gemm(const void* __restrict__ Ain,
                                              const ushort_t* __restrict__ Wt,
                                              const float* __restrict__ dinv,
                                              ushort_t* __restrict__ H) {
    const int t = threadIdx.x;
    const int wave = t >> 6;
    const int lane = t & 63;
    const int q = lane >> 4;       // quad 0..3
    const int r = lane & 15;
    const int row0 = blockIdx.x * 128 + wave * 32;

    f32x4 acc[2][8];
#pragma unroll
    for (int i = 0; i < 2; ++i)
#pragma unroll
        for (int j = 0; j < 8; ++j)
            acc[i][j] = (f32x4){0.f, 0.f, 0.f, 0.f};

#pragma unroll
    for (int ks = 0; ks < 4; ++ks) {
        const int k0 = ks * 32 + q * 8;
        bf16x8 a[2], b[8];
#pragma unroll
        for (int i = 0; i < 2; ++i) {
            if constexpr (F32A) {
                int rr = row0 + i * 16 + r;
                if (rr > N_NODES - 1) rr = N_NODES - 1;   // clamp: x is exactly N_NODES rows
                const float* p = (const float*)Ain + (size_t)rr * 128 + k0;
                float4 v0 = *(const float4*)p;
                float4 v1 = *(const float4*)(p + 4);
                bf16x8 av;
                av[0] = (short)f2bf(v0.x); av[1] = (short)f2bf(v0.y);
                av[2] = (short)f2bf(v0.z); av[3] = (short)f2bf(v0.w);
                av[4] = (short)f2bf(v1.x); av[5] = (short)f2bf(v1.y);
                av[6] = (short)f2bf(v1.z); av[7] = (short)f2bf(v1.w);
                a[i] = av;
            } else {
                a[i] = *(const bf16x8*)((const ushort_t*)Ain + (size_t)(row0 + i * 16 + r) * 128 + k0);
            }
        }
#pragma unroll
        for (int j = 0; j < 8; ++j)
            b[j] = *(const bf16x8*)(Wt + (size_t)(j * 16 + r) * 128 + k0);
#pragma unroll
        for (int i = 0; i < 2; ++i)
#pragma unroll
            for (int j = 0; j < 8; ++j)
                acc[i][j] = __builtin_amdgcn_mfma_f32_16x16x32_bf16(a[i], b[j], acc[i][j], 0, 0, 0);
    }

#pragma unroll
    for (int i = 0; i < 2; ++i) {
#pragma unroll
        for (int rg = 0; rg < 4; ++rg) {
            int rr = row0 + i * 16 + q * 4 + rg;
            if (rr < N_NODES) {
                float dv = dinv[rr];
#pragma unroll
                for (int j = 0; j < 8; ++j)
                    H[(size_t)rr * 128 + j * 16 + r] = f2bf(acc[i][j][rg] * dv);
            }
        }
    }
}

// ---------------- gather-aggregate v3: one wave per dst node, 4 edges per pass ----------------
// 16 lanes per edge, uint4 (16B) loads.
// AGG (bf16) = dinv[i]*(sum_nbr Hs + Hs[i]) + b
__global__ __launch_bounds__(256) void k_gather(const int* __restrict__ csr_src,
                                                const int* __restrict__ offs,
                                                const float* __restrict__ dinv,
                                                const ushort_t* __restrict__ H,
                                                const float* __restrict__ b,
                                                ushort_t* __restrict__ AGG) {
    int node = blockIdx.x * 4 + (threadIdx.x >> 6);
    if (node >= N_NODES) return;
    int lane = threadIdx.x & 63;
    int g = lane >> 4;             // edge slot within the quad (0..3)
    int cl = lane & 15;
    int c = cl * 8;                // 8 channels per lane

    float a0 = 0.f, a1 = 0.f, a2 = 0.f, a3 = 0.f;
    float a4 = 0.f, a5 = 0.f, a6 = 0.f, a7 = 0.f;

#define ACC8(hv)  do { \
        a0 += bf2f_lo((hv).x); a1 += bf2f_hi((hv).x); \
        a2 += bf2f_lo((hv).y); a3 += bf2f_hi((hv).y); \
        a4 += bf2f_lo((hv).z); a5 += bf2f_hi((hv).z); \
        a6 += bf2f_lo((hv).w); a7 += bf2f_hi((hv).w); } while (0)

    if (g == 0) {                  // self term (dinv-scaled H row)
        uint4 hv = *(const uint4*)(H + (size_t)node * 128 + c);
        ACC8(hv);
    }

    int p = offs[node];
    int end = offs[node + 1];

    for (; p + 16 <= end; p += 16) {          // 16 edges: 4 quad-loads in flight
        int s0 = csr_src[p      + g], s1 = csr_src[p +  4 + g];
        int s2 = csr_src[p +  8 + g], s3 = csr_src[p + 12 + g];
        uint4 h0 = *(const uint4*)(H + (size_t)s0 * 128 + c);
        uint4 h1 = *(const uint4*)(H + (size_t)s1 * 128 + c);
        uint4 h2 = *(const uint4*)(H + (size_t)s2 * 128 + c);
        uint4 h3 = *(const uint4*)(H + (size_t)s3 * 128 + c);
        ACC8(h0); ACC8(h1); ACC8(h2); ACC8(h3);
    }
    for (; p + 4 <= end; p += 4) {            // 4 edges: 1 quad-load
        int s0 = csr_src[p + g];
        uint4 h0 = *(const uint4*)(H + (size_t)s0 * 128 + c);
        ACC8(h0);
    }
    if (p < end) {                            // tail: 1-3 edges, predicated
        int idx = p + g;
        bool ok = idx < end;
        int s0 = csr_src[ok ? idx : p];
        uint4 h0 = *(const uint4*)(H + (size_t)s0 * 128 + c);
        if (ok) ACC8(h0);
    }
#undef ACC8

    // combine the 4 edge groups: xor 16 then xor 32
    a0 += __shfl_xor(a0, 16); a1 += __shfl_xor(a1, 16);
    a2 += __shfl_xor(a2, 16); a3 += __shfl_xor(a3, 16);
    a4 += __shfl_xor(a4, 16); a5 += __shfl_xor(a5, 16);
    a6 += __shfl_xor(a6, 16); a7 += __shfl_xor(a7, 16);
    a0 += __shfl_xor(a0, 32); a1 += __shfl_xor(a1, 32);
    a2 += __shfl_xor(a2, 32); a3 += __shfl_xor(a3, 32);
    a4 += __shfl_xor(a4, 32); a5 += __shfl_xor(a5, 32);
    a6 += __shfl_xor(a6, 32); a7 += __shfl_xor(a7, 32);

    if (g == 0) {
        float dv = dinv[node];
        float4 bv0 = *(const float4*)&b[c];
        float4 bv1 = *(const float4*)&b[c + 4];
        a0 = a0 * dv + bv0.x; a1 = a1 * dv + bv0.y;
        a2 = a2 * dv + bv0.z; a3 = a3 * dv + bv0.w;
        a4 = a4 * dv + bv1.x; a5 = a5 * dv + bv1.y;
        a6 = a6 * dv + bv1.z; a7 = a7 * dv + bv1.w;
        uint4 o;
        o.x = (uint)f2bf(a0) | ((uint)f2bf(a1) << 16);
        o.y = (uint)f2bf(a2) | ((uint)f2bf(a3) << 16);
        o.z = (uint)f2bf(a4) | ((uint)f2bf(a5) << 16);
        o.w = (uint)f2bf(a6) | ((uint)f2bf(a7) << 16);
        *(uint4*)(AGG + (size_t)node * 128 + c) = o;
    }
}

// ---------------- BN stats: per-channel sum / sumsq (bf16 in) ----------------
__global__ __launch_bounds__(128) void k_bn_stats(const ushort_t* __restrict__ AGG,
                                                  float* __restrict__ stats) {
    int c = threadIdx.x;
    float s = 0.f, q = 0.f;
    for (int i = blockIdx.x; i < N_NODES; i += gridDim.x) {
        float v = bf2f(AGG[(size_t)i * 128 + c]);
        s += v;
        q += v * v;
    }
    atomicAdd(&stats[c], s);
    atomicAdd(&stats[128 + c], q);
}

// ---------------- BN apply (finalize fused) + ReLU (+ bf16 residual), bf16 out ----------------
__global__ __launch_bounds__(256) void k_bn_apply(const ushort_t* __restrict__ AGG,
                                                  const float* __restrict__ stats,
                                                  const float* __restrict__ gamma,
                                                  const float* __restrict__ beta,
                                                  const ushort_t* __restrict__ RES,  // may be null
                                                  ushort_t* __restrict__ OUT) {
    int tid = blockIdx.x * 256 + threadIdx.x;
    if (tid >= N_NODES * 32) return;
    int i = tid >> 5;
    int c = (tid & 31) * 4;

    const float invN = 1.0f / (float)N_NODES;
    float4 sm = *(const float4*)&stats[c];
    float4 sq = *(const float4*)&stats[128 + c];
    float4 gm = *(const float4*)&gamma[c];
    float4 bt = *(const float4*)&beta[c];
    float mu0 = sm.x * invN, mu1 = sm.y * invN, mu2 = sm.z * invN, mu3 = sm.w * invN;
    float sc0 = gm.x * rsqrtf(sq.x * invN - mu0 * mu0 + BN_EPS);
    float sc1 = gm.y * rsqrtf(sq.y * invN - mu1 * mu1 + BN_EPS);
    float sc2 = gm.z * rsqrtf(sq.z * invN - mu2 * mu2 + BN_EPS);
    float sc3 = gm.w * rsqrtf(sq.w * invN - mu3 * mu3 + BN_EPS);
    float sh0 = bt.x - mu0 * sc0, sh1 = bt.y - mu1 * sc1;
    float sh2 = bt.z - mu2 * sc2, sh3 = bt.w - mu3 * sc3;

    uint2 av = *(const uint2*)&AGG[(size_t)i * 128 + c];
    float y0 = bf2f((ushort_t)(av.x & 0xffff)) * sc0 + sh0;
    float y1 = bf2f((ushort_t)(av.x >> 16))    * sc1 + sh1;
    float y2 = bf2f((ushort_t)(av.y & 0xffff)) * sc2 + sh2;
    float y3 = bf2f((ushort_t)(av.y >> 16))    * sc3 + sh3;
    if (RES) {
        ushort4 rv = *(const ushort4*)&RES[(size_t)i * 128 + c];
        y0 += bf2f(rv.x); y1 += bf2f(rv.y); y2 += bf2f(rv.z); y3 += bf2f(rv.w);
    }
    ushort4 o;
    o.x = f2bf(fmaxf(y0, 0.f)); o.y = f2bf(fmaxf(y1, 0.f));
    o.z = f2bf(fmaxf(y2, 0.f)); o.w = f2bf(fmaxf(y3, 0.f));
    *(ushort4*)&OUT[(size_t)i * 128 + c] = o;
}

// ---------------- pooling: segmented reduction over sorted batch (bf16 in) ----------------
#define POOL_CHUNK 100
__global__ __launch_bounds__(128) void k_pool(const ushort_t* __restrict__ X,
                                              const int* __restrict__ batch,
                                              float* __restrict__ psum,
                                              uint* __restrict__ pmax,
                                              float* __restrict__ pcnt) {
    int t = threadIdx.x;                        // channel
    int i0 = blockIdx.x * POOL_CHUNK;
    int i1 = min(i0 + POOL_CHUNK, N_NODES);
    if (i0 >= i1) return;

    int cur = batch[i0];
    float s = 0.f, m = 0.f, cntf = 0.f;
    for (int i = i0; i < i1; ++i) {
        int b = batch[i];
        float v = bf2f(X[(size_t)i * 128 + t]);
        if (b != cur) {
            atomicAdd(&psum[cur * 128 + t], s);
            atomicMax(&pmax[cur * 128 + t], __float_as_uint(m));
            if (t == 0) atomicAdd(&pcnt[cur], cntf);
            s = 0.f; m = 0.f; cntf = 0.f;
            cur = b;
        }
        s += v;
        m = fmaxf(m, v);
        cntf += 1.f;
    }
    atomicAdd(&psum[cur * 128 + t], s);
    atomicMax(&pmax[cur * 128 + t], __float_as_uint(m));
    if (t == 0) atomicAdd(&pcnt[cur], cntf);
}

// ---------------- head ----------------
__global__ __launch_bounds__(64) void k_head(const float* __restrict__ psum,
                                             const uint* __restrict__ pmax,
                                             const float* __restrict__ pcnt,
                                             const float* __restrict__ Wh,
                                             const float* __restrict__ bh,
                                             float* __restrict__ out) {
    int g = blockIdx.x;
    int o = threadIdx.x;
    float cnt = pcnt[g];
    float inv = 1.0f / fmaxf(cnt, 1.0f);
    float acc = bh[o];
    for (int c = 0; c < 128; ++c) {
        float s = psum[g * 128 + c];
        float m = __uint_as_float(pmax[g * 128 + c]);
        acc += (s * inv) * Wh[c * 64 + o];
        acc += s * Wh[(128 + c) * 64 + o];
        acc += m * Wh[(256 + c) * 64 + o];
    }
    out[g * 64 + o] = acc;
}

// ---------------- host orchestration ----------------
extern "C" void kernel_launch(void* const* d_in, const int* in_sizes, int n_in,
                              void* d_out, int out_size, void* d_ws, size_t ws_size,
                              hipStream_t stream) {
    const float* x     = (const float*)d_in[0];
    const int*   ei    = (const int*)d_in[1];
    const int*   batch = (const int*)d_in[2];
    const float* W1 = (const float*)d_in[3];
    const float* b1 = (const float*)d_in[4];
    const float* g1 = (const float*)d_in[5];
    const float* be1= (const float*)d_in[6];
    const float* W2 = (const float*)d_in[7];
    const float* b2 = (const float*)d_in[8];
    const float* g2 = (const float*)d_in[9];
    const float* be2= (const float*)d_in[10];
    const float* W3 = (const float*)d_in[11];
    const float* b3 = (const float*)d_in[12];
    const float* g3 = (const float*)d_in[13];
    const float* be3= (const float*)d_in[14];
    const float* Wh = (const float*)d_in[15];
    const float* bh = (const float*)d_in[16];

    const int* src = ei;
    const int* dst = ei + N_EDGES;

    char* ws = (char*)d_ws;
    size_t off = 0;

    // ---- zero-initialized contiguous region (single memset) ----
    char* zero_base = ws;
    int*   cnt     = (int*)(ws + off);      off += 6553600;                      // N_NODES*CNT_STRIDE*4 padded
    float* stats   = (float*)(ws + off);    off += 3 * 512 * 4;                  // 3 layers x 512 floats
    float* psum    = (float*)(ws + off);    off += (size_t)N_GRAPHS * CH * 4;
    uint*  pmax    = (uint*)(ws + off);     off += (size_t)N_GRAPHS * CH * 4;
    float* pcnt    = (float*)(ws + off);    off += 4096;
    size_t zero_bytes = off;

    // csr_src aliases cnt: last read of cnt is k_scan3, first write of csr_src is k_fill
    int* csr_src = (int*)cnt;                                                    // N_EDGES*4 = 6.4MB <= 6553600

    // ---- uninitialized scratch ----
    float* dinv    = (float*)(ws + off);    off += 512 * 1024;
    ushort_t* XBA  = (ushort_t*)(ws + off); off += (size_t)N_PAD * CH * 2;
    ushort_t* XBB  = (ushort_t*)(ws + off); off += (size_t)N_PAD * CH * 2;
    ushort_t* H    = (ushort_t*)(ws + off); off += (size_t)N_PAD * CH * 2;
    ushort_t* AGG  = (ushort_t*)(ws + off); off += (size_t)N_NODES * CH * 2;
    ushort_t* Wt   = (ushort_t*)(ws + off); off += 3 * 16384 * 2;
    int*   lofs    = (int*)(ws + off);      off += 512 * 1024;
    int*   offs    = (int*)(ws + off);      off += 512 * 1024;      // N+1 ints
    int*   bsum    = (int*)(ws + off);      off += 4096;
    int*   rank    = (int*)(ws + off);      off += (size_t)N_EDGES * 4;

    const int SCAN_BLOCKS = (N_NODES + 511) / 512;   // 196

    hipMemsetAsync(zero_base, 0, zero_bytes, stream);

    // weight transpose + cast (x cast now folded into layer-1 gemm)
    k_precast<<<PREP_BLOCKS, 256, 0, stream>>>(W1, W2, W3, Wt);

    // degree(+rank) / scan(+dinv) / CSR fill
    k_deg<<<(N_EDGES + 255) / 256, 256, 0, stream>>>(dst, cnt, rank);
    k_scan1<<<SCAN_BLOCKS, 512, 0, stream>>>(cnt, lofs, bsum);
    k_scan2<<<1, 256, 0, stream>>>(bsum, SCAN_BLOCKS);
    k_scan3<<<(N_NODES + 255) / 256, 256, 0, stream>>>(lofs, bsum, cnt, offs, dinv);
    k_fill<<<(N_EDGES + 255) / 256, 256, 0, stream>>>(src, dst, offs, rank, csr_src);

    const int gemm_grid   = (N_NODES + 127) / 128;   // 782
    const int gather_grid = (N_NODES + 3) / 4;
    const int apply_grid  = (N_NODES * 32 + 255) / 256;
    const int pool_grid   = (N_NODES + POOL_CHUNK - 1) / POOL_CHUNK;

    struct Layer { const void* in; ushort_t* out; const ushort_t* Wt; const float* b;
                   const float* gm; const float* bt; const ushort_t* res; };
    Layer layers[3] = {
        { (const void*)x,   XBB, Wt,             b1, g1, be1, nullptr },
        { (const void*)XBB, XBA, Wt + 16384,     b2, g2, be2, XBB     },
        { (const void*)XBA, XBB, Wt + 2 * 16384, b3, g3, be3, XBA     },
    };

    for (int l = 0; l < 3; ++l) {
        const Layer& L = layers[l];
        float* st = stats + l * 512;
        if (l == 0)
            k_gemm<true><<<gemm_grid, 256, 0, stream>>>(L.in, L.Wt, dinv, H);
        else
            k_gemm<false><<<gemm_grid, 256, 0, stream>>>(L.in, L.Wt, dinv, H);
        k_gather<<<gather_grid, 256, 0, stream>>>(csr_src, offs, dinv, H, L.b, AGG);
        k_bn_stats<<<1024, 128, 0, stream>>>(AGG, st);
        k_bn_apply<<<apply_grid, 256, 0, stream>>>(AGG, st, L.gm, L.bt, L.res, L.out);
    }

    // pooling (layer-3 output is in XBB)
    k_pool<<<pool_grid, 128, 0, stream>>>(XBB, batch, psum, pmax, pcnt);
    k_head<<<N_GRAPHS, 64, 0, stream>>>(psum, pmax, pcnt, Wh, bh, (float*)d_out);
}